// Round 1
// baseline (506.657 us; speedup 1.0000x reference)
//
#include <hip/hip_runtime.h>

#define B_   4
#define N_   2048
#define DIM  128
#define NH   8
#define HD   16
#define FFN_ 256
#define LN_EPS 1e-5f
#define BN   (B_*N_)

// ---------------- adj (int32 0/1) -> 64-bit masks ----------------
__global__ __launch_bounds__(256) void k_adjbits(const int* __restrict__ adj,
                                                 unsigned long long* __restrict__ bits) {
    long long idx = (long long)blockIdx.x * 256 + threadIdx.x;
    int v = adj[idx] != 0;
    unsigned long long m = __ballot(v);
    if ((threadIdx.x & 63) == 0) bits[idx >> 6] = m;
}

// ---------------- fused QKV projection ----------------
// grid: BN/32 blocks, 256 threads. 32 rows of h staged in LDS.
__global__ __launch_bounds__(256) void k_qkv(const float* __restrict__ h,
    const float* __restrict__ Wq, const float* __restrict__ Wk, const float* __restrict__ Wv,
    float* __restrict__ Q, float* __restrict__ K, float* __restrict__ V) {
    __shared__ float hs[32][DIM];
    const int r0  = blockIdx.x * 32;
    const int tid = threadIdx.x;
    for (int i = tid; i < 32 * DIM; i += 256)
        hs[i >> 7][i & 127] = h[(long long)r0 * DIM + i];
    __syncthreads();
    const int c     = tid & 127;
    const int rbase = (tid >> 7) * 16;
    float aq[16], ak[16], av[16];
    #pragma unroll
    for (int i = 0; i < 16; ++i) { aq[i] = 0.f; ak[i] = 0.f; av[i] = 0.f; }
    for (int k = 0; k < DIM; ++k) {
        float wq = Wq[k * DIM + c], wk = Wk[k * DIM + c], wv = Wv[k * DIM + c];
        #pragma unroll
        for (int i = 0; i < 16; ++i) {
            float hv = hs[rbase + i][k];
            aq[i] += hv * wq; ak[i] += hv * wk; av[i] += hv * wv;
        }
    }
    #pragma unroll
    for (int i = 0; i < 16; ++i) {
        long long o = (long long)(r0 + rbase + i) * DIM + c;
        Q[o] = aq[i]; K[o] = ak[i]; V[o] = av[i];
    }
}

// ---------------- masked flash attention (fp32) ----------------
// grid: B*NH*(N/256) blocks, 256 threads; one thread per query row.
__global__ __launch_bounds__(256) void k_attn(
    const float* __restrict__ Q, const float* __restrict__ K, const float* __restrict__ V,
    const unsigned long long* __restrict__ adjb,
    float* __restrict__ AO) {
    const int bid = blockIdx.x;
    const int qt  = bid & 7;          // N/256 = 8 q-tiles
    const int hh  = (bid >> 3) & 7;   // head
    const int b   = bid >> 6;         // batch
    const int tid = threadIdx.x;
    const int q   = qt * 256 + tid;

    __shared__ float Kt[128][HD];
    __shared__ float Vt[128][HD];

    float qr[16];
    {
        const float4* qp = (const float4*)(Q + ((long long)(b * N_ + q)) * DIM + hh * HD);
        float4 a0 = qp[0], a1 = qp[1], a2 = qp[2], a3 = qp[3];
        qr[0]=a0.x; qr[1]=a0.y; qr[2]=a0.z; qr[3]=a0.w;
        qr[4]=a1.x; qr[5]=a1.y; qr[6]=a1.z; qr[7]=a1.w;
        qr[8]=a2.x; qr[9]=a2.y; qr[10]=a2.z; qr[11]=a2.w;
        qr[12]=a3.x; qr[13]=a3.y; qr[14]=a3.z; qr[15]=a3.w;
    }

    float rmax = -1e30f, rsum = 0.f;
    float acc[16];
    #pragma unroll
    for (int i = 0; i < 16; ++i) acc[i] = 0.f;

    for (int t = 0; t < N_ / 128; ++t) {
        __syncthreads();
        for (int j = tid; j < 512; j += 256) {          // 512 float4 per matrix
            int m = j >> 2, d4 = (j & 3) * 4;
            long long g = ((long long)(b * N_ + t * 128 + m)) * DIM + hh * HD + d4;
            *(float4*)&Kt[m][d4] = *(const float4*)&K[g];
            *(float4*)&Vt[m][d4] = *(const float4*)&V[g];
        }
        __syncthreads();

        unsigned long long w0 = adjb[(long long)q * 32 + t * 2];
        unsigned long long w1 = adjb[(long long)q * 32 + t * 2 + 1];

        for (int c = 0; c < 128; c += 8) {
            unsigned long long w = (c < 64) ? w0 : w1;
            unsigned cb = (unsigned)((w >> (c & 63)) & 0xffull);
            float s[8];
            #pragma unroll
            for (int j = 0; j < 8; ++j) {
                float d = 0.f;
                #pragma unroll
                for (int dd = 0; dd < 16; ++dd) d += qr[dd] * Kt[c + j][dd];
                s[j] = ((cb >> j) & 1u) ? d * 0.25f : -1e30f;
            }
            float cmax = fmaxf(fmaxf(fmaxf(s[0], s[1]), fmaxf(s[2], s[3])),
                               fmaxf(fmaxf(s[4], s[5]), fmaxf(s[6], s[7])));
            float nmax  = fmaxf(rmax, cmax);
            float scale = __expf(rmax - nmax);
            float p[8], psum = 0.f;
            #pragma unroll
            for (int j = 0; j < 8; ++j) {
                p[j] = ((cb >> j) & 1u) ? __expf(s[j] - nmax) : 0.f;
                psum += p[j];
            }
            rsum = rsum * scale + psum;
            rmax = nmax;
            #pragma unroll
            for (int dd = 0; dd < 16; ++dd) {
                float a = acc[dd] * scale;
                #pragma unroll
                for (int j = 0; j < 8; ++j) a += p[j] * Vt[c + j][dd];
                acc[dd] = a;
            }
        }
    }

    float inv = 1.f / rsum;
    float* op = AO + ((long long)(b * N_ + q)) * DIM + hh * HD;
    float4 o0 = {acc[0]*inv, acc[1]*inv, acc[2]*inv, acc[3]*inv};
    float4 o1 = {acc[4]*inv, acc[5]*inv, acc[6]*inv, acc[7]*inv};
    float4 o2 = {acc[8]*inv, acc[9]*inv, acc[10]*inv, acc[11]*inv};
    float4 o3 = {acc[12]*inv, acc[13]*inv, acc[14]*inv, acc[15]*inv};
    ((float4*)op)[0] = o0; ((float4*)op)[1] = o1;
    ((float4*)op)[2] = o2; ((float4*)op)[3] = o3;
}

// ---------------- Wo projection + residual + LN1 ----------------
// grid: BN/8 blocks, 128 threads; 8 rows per block.
__global__ __launch_bounds__(128) void k_proj_ln(
    const float* __restrict__ AO, const float* __restrict__ h,
    const float* __restrict__ Wo, const float* __restrict__ bo,
    const float* __restrict__ g, const float* __restrict__ bln,
    float* __restrict__ X) {
    const int r0 = blockIdx.x * 8;
    const int c  = threadIdx.x;
    __shared__ float a[8][DIM];
    __shared__ float vv[8][DIM];
    __shared__ float mu_s[8], rs_s[8];
    for (int i = c; i < 8 * DIM; i += 128)
        a[i >> 7][i & 127] = AO[(long long)r0 * DIM + i];
    __syncthreads();
    float accv[8];
    float bov = bo[c];
    #pragma unroll
    for (int r = 0; r < 8; ++r) accv[r] = bov;
    for (int k = 0; k < DIM; ++k) {
        float w = Wo[k * DIM + c];
        #pragma unroll
        for (int r = 0; r < 8; ++r) accv[r] += a[r][k] * w;
    }
    #pragma unroll
    for (int r = 0; r < 8; ++r)
        vv[r][c] = accv[r] + h[((long long)(r0 + r)) * DIM + c];
    __syncthreads();
    const int wv = c >> 6, ln = c & 63;
    for (int i = 0; i < 4; ++i) {
        int r = wv * 4 + i;
        float x0 = vv[r][ln], x1 = vv[r][ln + 64];
        float s = x0 + x1, s2 = x0 * x0 + x1 * x1;
        for (int off = 1; off < 64; off <<= 1) {
            s  += __shfl_xor(s,  off);
            s2 += __shfl_xor(s2, off);
        }
        if (ln == 0) {
            float mu = s * (1.f / DIM);
            float var = s2 * (1.f / DIM) - mu * mu;
            mu_s[r] = mu; rs_s[r] = rsqrtf(var + LN_EPS);
        }
    }
    __syncthreads();
    float gc = g[c], bc = bln[c];
    #pragma unroll
    for (int r = 0; r < 8; ++r)
        X[((long long)(r0 + r)) * DIM + c] = (vv[r][c] - mu_s[r]) * rs_s[r] * gc + bc;
}

// ---------------- FFN + residual + LN2 ----------------
// grid: BN/8 blocks, 256 threads; 8 rows per block.
__global__ __launch_bounds__(256) void k_ffn_ln(
    const float* __restrict__ X,
    const float* __restrict__ W1, const float* __restrict__ b1,
    const float* __restrict__ W2, const float* __restrict__ b2,
    const float* __restrict__ g, const float* __restrict__ bln,
    float* __restrict__ out) {
    const int r0  = blockIdx.x * 8;
    const int tid = threadIdx.x;
    __shared__ float xs[8][DIM];
    __shared__ float ts[8][FFN_];
    __shared__ float vv[8][DIM];
    __shared__ float mu_s[8], rs_s[8];
    for (int i = tid; i < 8 * DIM; i += 256)
        xs[i >> 7][i & 127] = X[(long long)r0 * DIM + i];
    __syncthreads();
    {
        float accv[8];
        float bb = b1[tid];
        #pragma unroll
        for (int r = 0; r < 8; ++r) accv[r] = bb;
        for (int k = 0; k < DIM; ++k) {
            float w = W1[k * FFN_ + tid];
            #pragma unroll
            for (int r = 0; r < 8; ++r) accv[r] += xs[r][k] * w;
        }
        #pragma unroll
        for (int r = 0; r < 8; ++r) ts[r][tid] = fmaxf(accv[r], 0.f);
    }
    __syncthreads();
    {
        const int c = tid & 127, rg = tid >> 7;
        float y[4];
        float bb = b2[c];
        #pragma unroll
        for (int i = 0; i < 4; ++i) y[i] = bb;
        for (int k = 0; k < FFN_; ++k) {
            float w = W2[k * DIM + c];
            #pragma unroll
            for (int i = 0; i < 4; ++i) y[i] += ts[rg * 4 + i][k] * w;
        }
        #pragma unroll
        for (int i = 0; i < 4; ++i) vv[rg * 4 + i][c] = y[i] + xs[rg * 4 + i][c];
    }
    __syncthreads();
    {
        const int wv = tid >> 6, ln = tid & 63;
        for (int i = 0; i < 2; ++i) {
            int rr = wv * 2 + i;
            float x0 = vv[rr][ln], x1 = vv[rr][ln + 64];
            float s = x0 + x1, s2 = x0 * x0 + x1 * x1;
            for (int off = 1; off < 64; off <<= 1) {
                s  += __shfl_xor(s,  off);
                s2 += __shfl_xor(s2, off);
            }
            if (ln == 0) {
                float mu = s * (1.f / DIM);
                float var = s2 * (1.f / DIM) - mu * mu;
                mu_s[rr] = mu; rs_s[rr] = rsqrtf(var + LN_EPS);
            }
        }
    }
    __syncthreads();
    {
        const int c = tid & 127, rg = tid >> 7;
        float gc = g[c], bc = bln[c];
        #pragma unroll
        for (int i = 0; i < 4; ++i) {
            int rr = rg * 4 + i;
            out[((long long)(r0 + rr)) * DIM + c] =
                (vv[rr][c] - mu_s[rr]) * rs_s[rr] * gc + bc;
        }
    }
}

extern "C" void kernel_launch(void* const* d_in, const int* in_sizes, int n_in,
                              void* d_out, int out_size, void* d_ws, size_t ws_size,
                              hipStream_t stream) {
    const int*   adj = (const int*)  d_in[0];
    const float* h   = (const float*)d_in[1];
    const float* Wq  = (const float*)d_in[2];
    const float* Wk  = (const float*)d_in[3];
    const float* Wv  = (const float*)d_in[4];
    const float* Wo  = (const float*)d_in[5];
    const float* bo  = (const float*)d_in[6];
    const float* g1  = (const float*)d_in[7];
    const float* b1l = (const float*)d_in[8];
    const float* W1  = (const float*)d_in[9];
    const float* b1  = (const float*)d_in[10];
    const float* W2  = (const float*)d_in[11];
    const float* b2  = (const float*)d_in[12];
    const float* g2  = (const float*)d_in[13];
    const float* b2l = (const float*)d_in[14];
    float* out = (float*)d_out;

    float* ws = (float*)d_ws;
    float* Q  = ws;
    float* K  = Q  + (size_t)BN * DIM;
    float* V  = K  + (size_t)BN * DIM;
    float* AO = V  + (size_t)BN * DIM;
    float* X  = AO + (size_t)BN * DIM;
    unsigned long long* adjb = (unsigned long long*)(X + (size_t)BN * DIM);

    hipLaunchKernelGGL(k_adjbits, dim3(N_ * N_ / 256), dim3(256), 0, stream, adj, adjb);
    hipLaunchKernelGGL(k_qkv, dim3(BN / 32), dim3(256), 0, stream, h, Wq, Wk, Wv, Q, K, V);
    hipLaunchKernelGGL(k_attn, dim3(B_ * NH * (N_ / 256)), dim3(256), 0, stream,
                       Q, K, V, adjb, AO);
    hipLaunchKernelGGL(k_proj_ln, dim3(BN / 8), dim3(128), 0, stream,
                       AO, h, Wo, bo, g1, b1l, X);
    hipLaunchKernelGGL(k_ffn_ln, dim3(BN / 8), dim3(256), 0, stream,
                       X, W1, b1, W2, b2, g2, b2l, out);
}

// Round 2
// 160.115 us; speedup vs baseline: 3.1643x; 3.1643x over previous
//
#include <hip/hip_runtime.h>

#define B_   4
#define N_   2048
#define DIM  128
#define NH   8
#define HD   16
#define FFN_ 256
#define LN_EPS 1e-5f
#define BN   (B_*N_)

typedef __bf16 bf16x8 __attribute__((ext_vector_type(8)));
typedef __bf16 bf16x4 __attribute__((ext_vector_type(4)));
typedef short  s16x8  __attribute__((ext_vector_type(8)));
typedef float  f32x16 __attribute__((ext_vector_type(16)));

// ROCm clang declares __builtin_amdgcn_mfma_f32_32x32x16_bf16 with either
// <8 x bf16> or <8 x i16> operands depending on version. SFINAE both.
template<class T> struct as_short_vec { using type = s16x8; };

template <class T>
__device__ auto mfma_try(T a, T b, f32x16 c, int)
    -> decltype(__builtin_amdgcn_mfma_f32_32x32x16_bf16(a, b, c, 0, 0, 0)) {
  return __builtin_amdgcn_mfma_f32_32x32x16_bf16(a, b, c, 0, 0, 0);
}
template <class T>
__device__ f32x16 mfma_try(T a, T b, f32x16 c, long) {
  return __builtin_amdgcn_mfma_f32_32x32x16_bf16(
      __builtin_bit_cast(typename as_short_vec<T>::type, a),
      __builtin_bit_cast(typename as_short_vec<T>::type, b), c, 0, 0, 0);
}
__device__ __forceinline__ f32x16 mfma_bf(bf16x8 a, bf16x8 b, f32x16 c) {
  return mfma_try(a, b, c, 0);
}

// ---------------- adj (int32 0/1) -> 64-bit masks ----------------
__global__ __launch_bounds__(256) void k_adjbits(const int* __restrict__ adj,
                                                 unsigned long long* __restrict__ bits) {
    long long idx = (long long)blockIdx.x * 256 + threadIdx.x;
    int v = adj[idx] != 0;
    unsigned long long m = __ballot(v);
    if ((threadIdx.x & 63) == 0) bits[idx >> 6] = m;
}

// ---------------- fused QKV projection -> bf16, attention layouts ----------
// Qb,Kb: [B][H][N][HD] bf16 (Q pre-scaled by 0.25); Vt: [B][H][HD][N] bf16.
__global__ __launch_bounds__(256) void k_qkv(const float* __restrict__ h,
    const float* __restrict__ Wq, const float* __restrict__ Wk, const float* __restrict__ Wv,
    __bf16* __restrict__ Qb, __bf16* __restrict__ Kb, __bf16* __restrict__ Vt) {
    __shared__ float hs[32][DIM];
    const int r0  = blockIdx.x * 32;
    const int tid = threadIdx.x;
    for (int i = tid; i < 32 * DIM; i += 256)
        hs[i >> 7][i & 127] = h[(size_t)r0 * DIM + i];
    __syncthreads();
    const int c     = tid & 127;
    const int rbase = (tid >> 7) * 16;
    float aq[16], ak[16], av[16];
    #pragma unroll
    for (int i = 0; i < 16; ++i) { aq[i] = 0.f; ak[i] = 0.f; av[i] = 0.f; }
    for (int k = 0; k < DIM; ++k) {
        float wq = Wq[k * DIM + c], wk = Wk[k * DIM + c], wv = Wv[k * DIM + c];
        #pragma unroll
        for (int i = 0; i < 16; ++i) {
            float hv = hs[rbase + i][k];
            aq[i] += hv * wq; ak[i] += hv * wk; av[i] += hv * wv;
        }
    }
    const int hh = c >> 4, d = c & 15;
    const int b  = r0 >> 11;
    const int n0 = (r0 & (N_ - 1)) + rbase;
    size_t qk = ((size_t)(b * NH + hh) * N_ + n0) * HD + d;
    size_t vt = ((size_t)(b * NH + hh) * HD + d) * N_ + n0;
    #pragma unroll
    for (int i = 0; i < 16; ++i) {
        Qb[qk + (size_t)i * HD] = (__bf16)(aq[i] * 0.25f);
        Kb[qk + (size_t)i * HD] = (__bf16)ak[i];
        Vt[vt + i]              = (__bf16)av[i];
    }
}

// ---------------- masked flash attention, MFMA 32x32x16 ----------------
// grid: B*H*(N/128) = 512 blocks x 256 thr; each wave owns 32 q-rows.
__global__ __launch_bounds__(256) void k_attn(
    const __bf16* __restrict__ Qb, const __bf16* __restrict__ Kb,
    const __bf16* __restrict__ Vt, const unsigned long long* __restrict__ adjb,
    float* __restrict__ AO) {
    const int bid  = blockIdx.x;
    const int qt   = bid & 15;
    const int hh   = (bid >> 4) & 7;
    const int b    = bid >> 7;
    const int wv   = threadIdx.x >> 6;
    const int lane = threadIdx.x & 63;
    const int l31  = lane & 31, hi = lane >> 5;
    const int q    = qt * 128 + wv * 32 + l31;

    const __bf16* Qh = Qb + (size_t)(b * NH + hh) * N_ * HD;
    const __bf16* Kh = Kb + (size_t)(b * NH + hh) * N_ * HD;
    const __bf16* Vh = Vt + (size_t)(b * NH + hh) * HD * N_ + (size_t)(l31 & 15) * N_;

    // Q^T B-frag: col q = l31, d = hi*8 + i (8 consecutive) — one 16B load.
    bf16x8 qf = *(const bf16x8*)(Qh + (size_t)q * HD + hi * 8);

    f32x16 acc;
    #pragma unroll
    for (int i = 0; i < 16; ++i) acc[i] = 0.f;
    float m = -1e30f, sum = 0.f;

    unsigned long long w64 = adjb[(size_t)q * (N_ / 64)];
    bf16x8 kf = *(const bf16x8*)(Kh + (size_t)l31 * HD + hi * 8);

    for (int t = 0; t < N_ / 32; ++t) {
        const int k0 = t * 32;
        // prefetch next K-frag / mask word
        bf16x8 kf_n = kf;
        if (t + 1 < N_ / 32)
            kf_n = *(const bf16x8*)(Kh + (size_t)(k0 + 32 + l31) * HD + hi * 8);
        unsigned long long w64_n = w64;
        if ((t & 1) && t + 1 < N_ / 32)
            w64_n = adjb[(size_t)q * (N_ / 64) + ((t + 1) >> 1)];

        // S^T[k][q] = K-tile x Q^T ; D: q = l31, k = (r&3)+8*(r>>2)+4*hi
        f32x16 z;
        #pragma unroll
        for (int i = 0; i < 16; ++i) z[i] = 0.f;
        f32x16 st = mfma_bf(kf, qf, z);

        const unsigned mm = (unsigned)(w64 >> ((t & 1) * 32));

        float s[16];
        #pragma unroll
        for (int r = 0; r < 16; ++r) {
            const int pos = (r & 3) + 8 * (r >> 2) + 4 * hi;
            s[r] = ((mm >> pos) & 1u) ? st[r] : -1e30f;
        }
        float tm = s[0];
        #pragma unroll
        for (int r = 1; r < 16; ++r) tm = fmaxf(tm, s[r]);
        tm = fmaxf(tm, __shfl_xor(tm, 32));
        const float mn    = fmaxf(m, tm);
        const float scale = __expf(m - mn);
        float p[16], ps = 0.f;
        #pragma unroll
        for (int r = 0; r < 16; ++r) {
            const int pos = (r & 3) + 8 * (r >> 2) + 4 * hi;
            float e = __expf(s[r] - mn);
            p[r] = ((mm >> pos) & 1u) ? e : 0.f;
            ps += p[r];
        }
        sum = sum * scale + (ps + __shfl_xor(ps, 32));
        m = mn;
        #pragma unroll
        for (int r = 0; r < 8; ++r) acc[r] *= scale;   // only dd<16 regs are used

        // P^T B-frags are own regs in ascending order (key permutation is
        // absorbed into the V^T A-operand addresses below).
        bf16x8 pa, pb;
        #pragma unroll
        for (int r = 0; r < 8; ++r) { pa[r] = (__bf16)p[r]; pb[r] = (__bf16)p[r + 8]; }

        const int off1 = k0 + hi * 4;   // lane-half key permutation
        bf16x4 va0 = *(const bf16x4*)(Vh + off1);
        bf16x4 va1 = *(const bf16x4*)(Vh + off1 + 8);
        bf16x4 vb0 = *(const bf16x4*)(Vh + off1 + 16);
        bf16x4 vb1 = *(const bf16x4*)(Vh + off1 + 24);
        bf16x8 vfa, vfb;
        #pragma unroll
        for (int i = 0; i < 4; ++i) {
            vfa[i] = va0[i]; vfa[4 + i] = va1[i];
            vfb[i] = vb0[i]; vfb[4 + i] = vb1[i];
        }
        acc = mfma_bf(vfa, pa, acc);
        acc = mfma_bf(vfb, pb, acc);

        kf = kf_n; w64 = w64_n;
    }

    const float inv = 1.f / sum;
    float* op = AO + ((size_t)(b * N_ + q)) * DIM + hh * HD + 4 * hi;
    float4 o0 = { acc[0] * inv, acc[1] * inv, acc[2] * inv, acc[3] * inv };
    float4 o1 = { acc[4] * inv, acc[5] * inv, acc[6] * inv, acc[7] * inv };
    *(float4*)op       = o0;   // dd = 4*hi + 0..3
    *(float4*)(op + 8) = o1;   // dd = 8 + 4*hi + 0..3
}

// ---------------- Wo projection + residual + LN1 ----------------
__global__ __launch_bounds__(128) void k_proj_ln(
    const float* __restrict__ AO, const float* __restrict__ h,
    const float* __restrict__ Wo, const float* __restrict__ bo,
    const float* __restrict__ g, const float* __restrict__ bln,
    float* __restrict__ X) {
    const int r0 = blockIdx.x * 8;
    const int c  = threadIdx.x;
    __shared__ float a[8][DIM];
    __shared__ float vv[8][DIM];
    __shared__ float mu_s[8], rs_s[8];
    for (int i = c; i < 8 * DIM; i += 128)
        a[i >> 7][i & 127] = AO[(long long)r0 * DIM + i];
    __syncthreads();
    float accv[8];
    float bov = bo[c];
    #pragma unroll
    for (int r = 0; r < 8; ++r) accv[r] = bov;
    for (int k = 0; k < DIM; ++k) {
        float w = Wo[k * DIM + c];
        #pragma unroll
        for (int r = 0; r < 8; ++r) accv[r] += a[r][k] * w;
    }
    #pragma unroll
    for (int r = 0; r < 8; ++r)
        vv[r][c] = accv[r] + h[((long long)(r0 + r)) * DIM + c];
    __syncthreads();
    const int wv = c >> 6, ln = c & 63;
    for (int i = 0; i < 4; ++i) {
        int r = wv * 4 + i;
        float x0 = vv[r][ln], x1 = vv[r][ln + 64];
        float s = x0 + x1, s2 = x0 * x0 + x1 * x1;
        for (int off = 1; off < 64; off <<= 1) {
            s  += __shfl_xor(s,  off);
            s2 += __shfl_xor(s2, off);
        }
        if (ln == 0) {
            float mu = s * (1.f / DIM);
            float var = s2 * (1.f / DIM) - mu * mu;
            mu_s[r] = mu; rs_s[r] = rsqrtf(var + LN_EPS);
        }
    }
    __syncthreads();
    float gc = g[c], bc = bln[c];
    #pragma unroll
    for (int r = 0; r < 8; ++r)
        X[((long long)(r0 + r)) * DIM + c] = (vv[r][c] - mu_s[r]) * rs_s[r] * gc + bc;
}

// ---------------- FFN + residual + LN2 ----------------
__global__ __launch_bounds__(256) void k_ffn_ln(
    const float* __restrict__ X,
    const float* __restrict__ W1, const float* __restrict__ b1,
    const float* __restrict__ W2, const float* __restrict__ b2,
    const float* __restrict__ g, const float* __restrict__ bln,
    float* __restrict__ out) {
    const int r0  = blockIdx.x * 8;
    const int tid = threadIdx.x;
    __shared__ float xs[8][DIM];
    __shared__ float ts[8][FFN_];
    __shared__ float vv[8][DIM];
    __shared__ float mu_s[8], rs_s[8];
    for (int i = tid; i < 8 * DIM; i += 256)
        xs[i >> 7][i & 127] = X[(long long)r0 * DIM + i];
    __syncthreads();
    {
        float accv[8];
        float bb = b1[tid];
        #pragma unroll
        for (int r = 0; r < 8; ++r) accv[r] = bb;
        for (int k = 0; k < DIM; ++k) {
            float w = W1[k * FFN_ + tid];
            #pragma unroll
            for (int r = 0; r < 8; ++r) accv[r] += xs[r][k] * w;
        }
        #pragma unroll
        for (int r = 0; r < 8; ++r) ts[r][tid] = fmaxf(accv[r], 0.f);
    }
    __syncthreads();
    {
        const int c = tid & 127, rg = tid >> 7;
        float y[4];
        float bb = b2[c];
        #pragma unroll
        for (int i = 0; i < 4; ++i) y[i] = bb;
        for (int k = 0; k < FFN_; ++k) {
            float w = W2[k * DIM + c];
            #pragma unroll
            for (int i = 0; i < 4; ++i) y[i] += ts[rg * 4 + i][k] * w;
        }
        #pragma unroll
        for (int i = 0; i < 4; ++i) vv[rg * 4 + i][c] = y[i] + xs[rg * 4 + i][c];
    }
    __syncthreads();
    {
        const int wv = tid >> 6, ln = tid & 63;
        for (int i = 0; i < 2; ++i) {
            int rr = wv * 2 + i;
            float x0 = vv[rr][ln], x1 = vv[rr][ln + 64];
            float s = x0 + x1, s2 = x0 * x0 + x1 * x1;
            for (int off = 1; off < 64; off <<= 1) {
                s  += __shfl_xor(s,  off);
                s2 += __shfl_xor(s2, off);
            }
            if (ln == 0) {
                float mu = s * (1.f / DIM);
                float var = s2 * (1.f / DIM) - mu * mu;
                mu_s[rr] = mu; rs_s[rr] = rsqrtf(var + LN_EPS);
            }
        }
    }
    __syncthreads();
    {
        const int c = tid & 127, rg = tid >> 7;
        float gc = g[c], bc = bln[c];
        #pragma unroll
        for (int i = 0; i < 4; ++i) {
            int rr = rg * 4 + i;
            out[((long long)(r0 + rr)) * DIM + c] =
                (vv[rr][c] - mu_s[rr]) * rs_s[rr] * gc + bc;
        }
    }
}

extern "C" void kernel_launch(void* const* d_in, const int* in_sizes, int n_in,
                              void* d_out, int out_size, void* d_ws, size_t ws_size,
                              hipStream_t stream) {
    const int*   adj = (const int*)  d_in[0];
    const float* h   = (const float*)d_in[1];
    const float* Wq  = (const float*)d_in[2];
    const float* Wk  = (const float*)d_in[3];
    const float* Wv  = (const float*)d_in[4];
    const float* Wo  = (const float*)d_in[5];
    const float* bo  = (const float*)d_in[6];
    const float* g1  = (const float*)d_in[7];
    const float* b1l = (const float*)d_in[8];
    const float* W1  = (const float*)d_in[9];
    const float* b1  = (const float*)d_in[10];
    const float* W2  = (const float*)d_in[11];
    const float* b2  = (const float*)d_in[12];
    const float* g2  = (const float*)d_in[13];
    const float* b2l = (const float*)d_in[14];
    float* out = (float*)d_out;

    float* AO = (float*)d_ws;                                  // BN*DIM f32
    float* X  = AO + (size_t)BN * DIM;                         // BN*DIM f32
    unsigned long long* adjb = (unsigned long long*)(X + (size_t)BN * DIM); // N*N/64
    __bf16* Qb = (__bf16*)(adjb + (size_t)N_ * N_ / 64);       // BN*DIM bf16
    __bf16* Kb = Qb + (size_t)BN * DIM;
    __bf16* Vt = Kb + (size_t)BN * DIM;

    hipLaunchKernelGGL(k_adjbits, dim3(N_ * N_ / 256), dim3(256), 0, stream, adj, adjb);
    hipLaunchKernelGGL(k_qkv, dim3(BN / 32), dim3(256), 0, stream, h, Wq, Wk, Wv, Qb, Kb, Vt);
    hipLaunchKernelGGL(k_attn, dim3(B_ * NH * (N_ / 128)), dim3(256), 0, stream,
                       Qb, Kb, Vt, adjb, AO);
    hipLaunchKernelGGL(k_proj_ln, dim3(BN / 8), dim3(128), 0, stream,
                       AO, h, Wo, bo, g1, b1l, X);
    hipLaunchKernelGGL(k_ffn_ln, dim3(BN / 8), dim3(256), 0, stream,
                       X, W1, b1, W2, b2, g2, b2l, out);
}

// Round 3
// 128.397 us; speedup vs baseline: 3.9460x; 1.2470x over previous
//
#include <hip/hip_runtime.h>

#define B_   4
#define N_   2048
#define DIM  128
#define NH   8
#define HD   16
#define FFN_ 256
#define LN_EPS 1e-5f
#define BN   (B_*N_)
#define LOG2E 1.44269504f
#define RESCALE_THR 12.0f   // log2 units (~8.3 nats)

typedef __bf16 bf16x8 __attribute__((ext_vector_type(8)));
typedef short  s16x8  __attribute__((ext_vector_type(8)));
typedef float  f32x16 __attribute__((ext_vector_type(16)));

// ROCm clang declares __builtin_amdgcn_mfma_f32_32x32x16_bf16 with either
// <8 x bf16> or <8 x i16> operands depending on version. SFINAE both.
template<class T> struct as_short_vec { using type = s16x8; };

template <class T>
__device__ auto mfma_try(T a, T b, f32x16 c, int)
    -> decltype(__builtin_amdgcn_mfma_f32_32x32x16_bf16(a, b, c, 0, 0, 0)) {
  return __builtin_amdgcn_mfma_f32_32x32x16_bf16(a, b, c, 0, 0, 0);
}
template <class T>
__device__ f32x16 mfma_try(T a, T b, f32x16 c, long) {
  return __builtin_amdgcn_mfma_f32_32x32x16_bf16(
      __builtin_bit_cast(typename as_short_vec<T>::type, a),
      __builtin_bit_cast(typename as_short_vec<T>::type, b), c, 0, 0, 0);
}
__device__ __forceinline__ f32x16 mfma_bf(bf16x8 a, bf16x8 b, f32x16 c) {
  return mfma_try(a, b, c, 0);
}

// ---------------- adj (int32 0/1) -> 64-bit masks ----------------
__global__ __launch_bounds__(256) void k_adjbits(const int* __restrict__ adj,
                                                 unsigned long long* __restrict__ bits) {
    long long idx = (long long)blockIdx.x * 256 + threadIdx.x;
    int v = adj[idx] != 0;
    unsigned long long m = __ballot(v);
    if ((threadIdx.x & 63) == 0) bits[idx >> 6] = m;
}

// ---------------- fused QKV projection -> bf16, attention layouts ----------
// Qb,Kb: [B][H][N][HD] bf16 (Q pre-scaled by 0.25*log2e); Vt: [B][H][HD][N] bf16
// with keys permuted within each 32-block: 4-group order [0,2,1,3,4,6,5,7]
// so PV A-fragments are straight bf16x8 loads.
__global__ __launch_bounds__(256) void k_qkv(const float* __restrict__ h,
    const float* __restrict__ Wq, const float* __restrict__ Wk, const float* __restrict__ Wv,
    __bf16* __restrict__ Qb, __bf16* __restrict__ Kb, __bf16* __restrict__ Vt) {
    __shared__ float hs[16][DIM];
    const int r0  = blockIdx.x * 16;
    const int tid = threadIdx.x;
    for (int i = tid; i < 16 * DIM; i += 256)
        hs[i >> 7][i & 127] = h[(size_t)r0 * DIM + i];
    __syncthreads();
    const int c     = tid & 127;
    const int rbase = (tid >> 7) * 8;
    float aq[8], ak[8], av[8];
    #pragma unroll
    for (int i = 0; i < 8; ++i) { aq[i] = 0.f; ak[i] = 0.f; av[i] = 0.f; }
    for (int k4 = 0; k4 < DIM; k4 += 4) {
        float4 hv[8];
        #pragma unroll
        for (int r = 0; r < 8; ++r) hv[r] = *(const float4*)&hs[rbase + r][k4];
        #pragma unroll
        for (int kk = 0; kk < 4; ++kk) {
            const int k = k4 + kk;
            float wq = Wq[k * DIM + c], wk = Wk[k * DIM + c], wv = Wv[k * DIM + c];
            #pragma unroll
            for (int r = 0; r < 8; ++r) {
                float hvv = ((const float*)&hv[r])[kk];
                aq[r] += hvv * wq; ak[r] += hvv * wk; av[r] += hvv * wv;
            }
        }
    }
    const int hh = c >> 4, d = c & 15;
    const int b  = r0 >> 11;
    const int n0 = (r0 & (N_ - 1)) + rbase;
    size_t qk = ((size_t)(b * NH + hh) * N_ + n0) * HD + d;
    size_t vh = ((size_t)(b * NH + hh) * HD + d) * N_;
    #pragma unroll
    for (int i = 0; i < 8; ++i) {
        Qb[qk + (size_t)i * HD] = (__bf16)(aq[i] * (0.25f * LOG2E));
        Kb[qk + (size_t)i * HD] = (__bf16)ak[i];
        int n  = n0 + i;
        int g  = (n >> 2) & 7;
        int ng = (g & 4) | ((g & 1) << 1) | ((g >> 1) & 1);
        Vt[vh + ((n & ~31) | (ng << 2) | (n & 3))] = (__bf16)av[i];
    }
}

// ---------------- masked flash attention, MFMA 32x32x16, split-K ----------
// grid: B*H*(N/128) = 512 blocks x 512 thr (8 waves).
// waves 0-3: keys 0..1023 for 128 q-rows; waves 4-7: keys 1024..2047.
// LDS merge at the end.
__global__ __launch_bounds__(512, 4) void k_attn(
    const __bf16* __restrict__ Qb, const __bf16* __restrict__ Kb,
    const __bf16* __restrict__ Vt, const unsigned long long* __restrict__ adjb,
    float* __restrict__ AO) {
    const int bid  = blockIdx.x;
    const int qt   = bid & 15;
    const int hh   = (bid >> 4) & 7;
    const int b    = bid >> 7;
    const int wv   = threadIdx.x >> 6;
    const int wq   = wv & 3;
    const int half = wv >> 2;
    const int lane = threadIdx.x & 63;
    const int l31  = lane & 31, hi = lane >> 5;
    const int q     = qt * 128 + wq * 32 + l31;
    const int kbase = half * (N_ / 2);

    __shared__ float accL[4][64][9];
    __shared__ float mL[4][32], sL[4][32];

    const __bf16* Qh = Qb + (size_t)(b * NH + hh) * N_ * HD;
    const __bf16* Kh = Kb + (size_t)(b * NH + hh) * N_ * HD;
    const __bf16* Vh = Vt + (size_t)(b * NH + hh) * HD * N_ + (size_t)(l31 & 15) * N_;

    // Q^T B-frag: col q = l31, d = hi*8 + i — one 16B load.
    bf16x8 qf = *(const bf16x8*)(Qh + (size_t)q * HD + hi * 8);

    f32x16 acc;
    #pragma unroll
    for (int i = 0; i < 16; ++i) acc[i] = 0.f;
    float m = -1e30f, sum = 0.f;

    const unsigned long long* wp = adjb + (size_t)q * (N_ / 64) + half * (N_ / 128);
    unsigned long long w64 = wp[0];
    bf16x8 kf  = *(const bf16x8*)(Kh + (size_t)(kbase + l31) * HD + hi * 8);
    bf16x8 vfa = *(const bf16x8*)(Vh + kbase + hi * 8);
    bf16x8 vfb = *(const bf16x8*)(Vh + kbase + 16 + hi * 8);

    for (int t = 0; t < N_ / 64; ++t) {
        // prefetch tile t+1
        bf16x8 kf_n = kf, vfa_n = vfa, vfb_n = vfb;
        unsigned long long w64_n = w64;
        if (t + 1 < N_ / 64) {
            const int k1 = kbase + (t + 1) * 32;
            kf_n  = *(const bf16x8*)(Kh + (size_t)(k1 + l31) * HD + hi * 8);
            vfa_n = *(const bf16x8*)(Vh + k1 + hi * 8);
            vfb_n = *(const bf16x8*)(Vh + k1 + 16 + hi * 8);
            if (t & 1) w64_n = wp[(t + 1) >> 1];
        }

        // S^T[k][q] (log2-scaled): D: q = l31, k = (r&3)+8*(r>>2)+4*hi
        f32x16 z;
        #pragma unroll
        for (int i = 0; i < 16; ++i) z[i] = 0.f;
        f32x16 st = mfma_bf(kf, qf, z);

        // tile max over raw scores (masked entries same distribution: safe)
        float a0 = fmaxf(fmaxf(st[0], st[1]), st[2]);
        float a1 = fmaxf(fmaxf(st[3], st[4]), st[5]);
        float a2 = fmaxf(fmaxf(st[6], st[7]), st[8]);
        float a3 = fmaxf(fmaxf(st[9], st[10]), st[11]);
        float a4 = fmaxf(fmaxf(st[12], st[13]), st[14]);
        float b0 = fmaxf(fmaxf(a0, a1), a2);
        float b1 = fmaxf(fmaxf(a3, a4), st[15]);
        float tm = fmaxf(b0, b1);
        tm = fmaxf(tm, __shfl_xor(tm, 32));

        // deferred rescale (T13): usually skipped after warm-up
        if (__any(tm > m + RESCALE_THR)) {
            float mn = fmaxf(m, tm);
            float sc = exp2f(m - mn);
            sum *= sc;
            #pragma unroll
            for (int r = 0; r < 8; ++r) acc[r] *= sc;
            m = mn;
        }

        const unsigned mm = (unsigned)(w64 >> ((t & 1) * 32));
        float p[16];
        #pragma unroll
        for (int r = 0; r < 16; ++r) {
            const int pos = (r & 3) + 8 * (r >> 2) + 4 * hi;
            float e = exp2f(st[r] - m);
            p[r] = ((mm >> pos) & 1u) ? e : 0.f;
        }
        // pairwise sum tree
        float s0 = (p[0] + p[1]) + (p[2] + p[3]);
        float s1 = (p[4] + p[5]) + (p[6] + p[7]);
        float s2 = (p[8] + p[9]) + (p[10] + p[11]);
        float s3 = (p[12] + p[13]) + (p[14] + p[15]);
        float ps = (s0 + s1) + (s2 + s3);
        sum += ps + __shfl_xor(ps, 32);

        bf16x8 pa, pb;
        #pragma unroll
        for (int r = 0; r < 8; ++r) { pa[r] = (__bf16)p[r]; pb[r] = (__bf16)p[r + 8]; }

        acc = mfma_bf(vfa, pa, acc);
        acc = mfma_bf(vfb, pb, acc);

        kf = kf_n; vfa = vfa_n; vfb = vfb_n; w64 = w64_n;
    }

    // ---- split-K merge through LDS ----
    if (half == 0) {
        #pragma unroll
        for (int r = 0; r < 8; ++r) accL[wq][lane][r] = acc[r];
        if (hi == 0) { mL[wq][l31] = m; sL[wq][l31] = sum; }
    }
    __syncthreads();
    if (half == 1) {
        float m0 = mL[wq][l31], s0 = sL[wq][l31];
        float mM = fmaxf(m, m0);
        float e1 = exp2f(m - mM), e0 = exp2f(m0 - mM);
        float s  = s0 * e0 + sum * e1;
        float inv = 1.f / s;
        float o[8];
        #pragma unroll
        for (int r = 0; r < 8; ++r)
            o[r] = (accL[wq][lane][r] * e0 + acc[r] * e1) * inv;
        float* op = AO + ((size_t)(b * N_ + q)) * DIM + hh * HD + 4 * hi;
        float4 o0 = { o[0], o[1], o[2], o[3] };
        float4 o1 = { o[4], o[5], o[6], o[7] };
        *(float4*)op       = o0;   // d = 4*hi + 0..3
        *(float4*)(op + 8) = o1;   // d = 8 + 4*hi + 0..3
    }
}

// ---------------- Wo projection + residual + LN1 ----------------
__global__ __launch_bounds__(128) void k_proj_ln(
    const float* __restrict__ AO, const float* __restrict__ h,
    const float* __restrict__ Wo, const float* __restrict__ bo,
    const float* __restrict__ g, const float* __restrict__ bln,
    float* __restrict__ X) {
    const int r0 = blockIdx.x * 8;
    const int c  = threadIdx.x;
    __shared__ float a[8][DIM];
    __shared__ float vv[8][DIM];
    __shared__ float mu_s[8], rs_s[8];
    for (int i = c; i < 8 * DIM; i += 128)
        a[i >> 7][i & 127] = AO[(long long)r0 * DIM + i];
    __syncthreads();
    float accv[8];
    float bov = bo[c];
    #pragma unroll
    for (int r = 0; r < 8; ++r) accv[r] = bov;
    for (int k = 0; k < DIM; ++k) {
        float w = Wo[k * DIM + c];
        #pragma unroll
        for (int r = 0; r < 8; ++r) accv[r] += a[r][k] * w;
    }
    #pragma unroll
    for (int r = 0; r < 8; ++r)
        vv[r][c] = accv[r] + h[((long long)(r0 + r)) * DIM + c];
    __syncthreads();
    const int wv = c >> 6, ln = c & 63;
    for (int i = 0; i < 4; ++i) {
        int r = wv * 4 + i;
        float x0 = vv[r][ln], x1 = vv[r][ln + 64];
        float s = x0 + x1, s2 = x0 * x0 + x1 * x1;
        for (int off = 1; off < 64; off <<= 1) {
            s  += __shfl_xor(s,  off);
            s2 += __shfl_xor(s2, off);
        }
        if (ln == 0) {
            float mu = s * (1.f / DIM);
            float var = s2 * (1.f / DIM) - mu * mu;
            mu_s[r] = mu; rs_s[r] = rsqrtf(var + LN_EPS);
        }
    }
    __syncthreads();
    float gc = g[c], bc = bln[c];
    #pragma unroll
    for (int r = 0; r < 8; ++r)
        X[((long long)(r0 + r)) * DIM + c] = (vv[r][c] - mu_s[r]) * rs_s[r] * gc + bc;
}

// ---------------- FFN + residual + LN2 ----------------
__global__ __launch_bounds__(256) void k_ffn_ln(
    const float* __restrict__ X,
    const float* __restrict__ W1, const float* __restrict__ b1,
    const float* __restrict__ W2, const float* __restrict__ b2,
    const float* __restrict__ g, const float* __restrict__ bln,
    float* __restrict__ out) {
    const int r0  = blockIdx.x * 8;
    const int tid = threadIdx.x;
    __shared__ float xs[8][DIM];
    __shared__ float ts[8][FFN_];
    __shared__ float vv[8][DIM];
    __shared__ float mu_s[8], rs_s[8];
    for (int i = tid; i < 8 * DIM; i += 256)
        xs[i >> 7][i & 127] = X[(long long)r0 * DIM + i];
    __syncthreads();
    {
        float accv[8];
        float bb = b1[tid];
        #pragma unroll
        for (int r = 0; r < 8; ++r) accv[r] = bb;
        for (int k = 0; k < DIM; ++k) {
            float w = W1[k * FFN_ + tid];
            #pragma unroll
            for (int r = 0; r < 8; ++r) accv[r] += xs[r][k] * w;
        }
        #pragma unroll
        for (int r = 0; r < 8; ++r) ts[r][tid] = fmaxf(accv[r], 0.f);
    }
    __syncthreads();
    {
        const int c = tid & 127, rg = tid >> 7;
        float y[4];
        float bb = b2[c];
        #pragma unroll
        for (int i = 0; i < 4; ++i) y[i] = bb;
        for (int k = 0; k < FFN_; ++k) {
            float w = W2[k * DIM + c];
            #pragma unroll
            for (int i = 0; i < 4; ++i) y[i] += ts[rg * 4 + i][k] * w;
        }
        #pragma unroll
        for (int i = 0; i < 4; ++i) vv[rg * 4 + i][c] = y[i] + xs[rg * 4 + i][c];
    }
    __syncthreads();
    {
        const int wv = tid >> 6, ln = tid & 63;
        for (int i = 0; i < 2; ++i) {
            int rr = wv * 2 + i;
            float x0 = vv[rr][ln], x1 = vv[rr][ln + 64];
            float s = x0 + x1, s2 = x0 * x0 + x1 * x1;
            for (int off = 1; off < 64; off <<= 1) {
                s  += __shfl_xor(s,  off);
                s2 += __shfl_xor(s2, off);
            }
            if (ln == 0) {
                float mu = s * (1.f / DIM);
                float var = s2 * (1.f / DIM) - mu * mu;
                mu_s[rr] = mu; rs_s[rr] = rsqrtf(var + LN_EPS);
            }
        }
    }
    __syncthreads();
    {
        const int c = tid & 127, rg = tid >> 7;
        float gc = g[c], bc = bln[c];
        #pragma unroll
        for (int i = 0; i < 4; ++i) {
            int rr = rg * 4 + i;
            out[((long long)(r0 + rr)) * DIM + c] =
                (vv[rr][c] - mu_s[rr]) * rs_s[rr] * gc + bc;
        }
    }
}

extern "C" void kernel_launch(void* const* d_in, const int* in_sizes, int n_in,
                              void* d_out, int out_size, void* d_ws, size_t ws_size,
                              hipStream_t stream) {
    const int*   adj = (const int*)  d_in[0];
    const float* h   = (const float*)d_in[1];
    const float* Wq  = (const float*)d_in[2];
    const float* Wk  = (const float*)d_in[3];
    const float* Wv  = (const float*)d_in[4];
    const float* Wo  = (const float*)d_in[5];
    const float* bo  = (const float*)d_in[6];
    const float* g1  = (const float*)d_in[7];
    const float* b1l = (const float*)d_in[8];
    const float* W1  = (const float*)d_in[9];
    const float* b1  = (const float*)d_in[10];
    const float* W2  = (const float*)d_in[11];
    const float* b2  = (const float*)d_in[12];
    const float* g2  = (const float*)d_in[13];
    const float* b2l = (const float*)d_in[14];
    float* out = (float*)d_out;

    float* AO = (float*)d_ws;                                  // BN*DIM f32
    float* X  = AO + (size_t)BN * DIM;                         // BN*DIM f32
    unsigned long long* adjb = (unsigned long long*)(X + (size_t)BN * DIM); // N*N/64
    __bf16* Qb = (__bf16*)(adjb + (size_t)N_ * N_ / 64);       // BN*DIM bf16
    __bf16* Kb = Qb + (size_t)BN * DIM;
    __bf16* Vt = Kb + (size_t)BN * DIM;

    hipLaunchKernelGGL(k_adjbits, dim3(N_ * N_ / 256), dim3(256), 0, stream, adj, adjb);
    hipLaunchKernelGGL(k_qkv, dim3(BN / 16), dim3(256), 0, stream, h, Wq, Wk, Wv, Qb, Kb, Vt);
    hipLaunchKernelGGL(k_attn, dim3(B_ * NH * (N_ / 128)), dim3(512), 0, stream,
                       Qb, Kb, Vt, adjb, AO);
    hipLaunchKernelGGL(k_proj_ln, dim3(BN / 8), dim3(128), 0, stream,
                       AO, h, Wo, bo, g1, b1l, X);
    hipLaunchKernelGGL(k_ffn_ln, dim3(BN / 8), dim3(256), 0, stream,
                       X, W1, b1, W2, b2, g2, b2l, out);
}